// Round 2
// baseline (315.981 us; speedup 1.0000x reference)
//
#include <hip/hip_runtime.h>
#include <math.h>

// Problem constants (B, V, L1, D from the reference)
#define BB 1024
#define VV 64
#define LL 6
#define DD 512
#define CM_STRIDE_B (VV * VV * LL)  // 24576 floats per batch slab
#define CM_STRIDE_C (VV * LL)       // 384 floats per cause row
#define NROWS (VV * 3 * LL)         // 1152 distinct (v,cat,lag) rows

// ---------------------------------------------------------------------------
// Kernel 1 (fused): blocks [0,1024) do the per-(b,v) reductions over the
// causal matrix; blocks [1024,1097) compute the 73 "A" rows:
//   A1[v]   = var_table[v]   @ W1[0:512]     (64 rows)
//   A2[cat] = strength_tab[c]@ W1[512:1024]  (3 rows)
//   A3[lag] = lag_table[l]   @ W1[1024:1536] (6 rows)
// Reductions accumulate in fp64 so the discrete cat/lag decisions match the
// true values (a flipped decision is a full-row error ~2e-2).
// ---------------------------------------------------------------------------
__global__ __launch_bounds__(384) void k_reduce_a(
    const float* __restrict__ cm,
    const float* __restrict__ var_t,
    const float* __restrict__ str_t,
    const float* __restrict__ lag_t,
    const float* __restrict__ W1,
    int* __restrict__ idx,
    float* __restrict__ Aall)
{
    __shared__ double sss[384];
    __shared__ double sas[384];
    __shared__ float  sin_[DD];

    const int blk = blockIdx.x;
    const int t   = threadIdx.x;

    if (blk < BB) {
        // thread t owns (v = t/6, l = t%6); loop over causes c.
        // Loads are contiguous 384-float rows across the block -> coalesced.
        const float* p = cm + (size_t)blk * CM_STRIDE_B + t;
        double ss = 0.0, as = 0.0;
        #pragma unroll 16
        for (int c = 0; c < VV; ++c) {
            double x = (double)p[(size_t)c * CM_STRIDE_C];
            ss += x;
            as += fabs(x);
        }
        sss[t] = ss;
        sas[t] = as;
        __syncthreads();
        if (t < VV) {
            const int base = t * LL;
            double m = 0.0;
            #pragma unroll
            for (int l = 0; l < LL; ++l) m += sss[base + l];
            m *= (1.0 / (double)(VV * LL));
            const int cat = (m > 0.1) ? 1 : ((m < -0.1) ? 2 : 0);
            double best = sas[base];
            int bl = 0;
            #pragma unroll
            for (int l = 1; l < LL; ++l) {           // strict > == first-occurrence argmax
                double s = sas[base + l];
                if (s > best) { best = s; bl = l; }
            }
            idx[blk * VV + t] = cat * LL + bl;       // packed in [0,18)
        }
    } else {
        const int r = blk - BB;                      // 0..72
        const float* in;
        const float* W;
        if (r < VV)          { in = var_t + r * DD;            W = W1; }
        else if (r < VV + 3) { in = str_t + (r - VV) * DD;     W = W1 + (size_t)DD * DD; }
        else                 { in = lag_t + (r - VV - 3) * DD; W = W1 + (size_t)2 * DD * DD; }
        for (int k = t; k < DD; k += 384) sin_[k] = in[k];
        __syncthreads();
        for (int d = t; d < DD; d += 384) {
            float acc = 0.f;
            for (int k = 0; k < DD; ++k) acc += sin_[k] * W[(size_t)k * DD + d];
            Aall[r * DD + d] = acc;
        }
    }
}

// ---------------------------------------------------------------------------
// Kernel 2: lut[1152][512] = relu(h) @ W2 + b2, with
//   h[r][k] = A1[v(r)][k] + A2[cat(r)][k] + A3[lag(r)][k] + b1[k]
// computed on the fly (Aall is 146 KB, L1/L2-hot). Standard 64x64 fp32 tile,
// 256 threads, 4x4 micro-tile, K-tiles of 16.
// ---------------------------------------------------------------------------
#define TK 16
__global__ __launch_bounds__(256) void k_lut(
    const float* __restrict__ Aall,
    const float* __restrict__ b1,
    const float* __restrict__ W2,
    const float* __restrict__ b2,
    float* __restrict__ lut)
{
    __shared__ float As[TK][64];
    __shared__ float Bs[TK][64];

    const int r0 = blockIdx.x * 64;
    const int n0 = blockIdx.y * 64;
    const int t  = threadIdx.x;
    const int tx = t & 15;
    const int ty = t >> 4;

    float acc[4][4] = {{0.f, 0.f, 0.f, 0.f}, {0.f, 0.f, 0.f, 0.f},
                       {0.f, 0.f, 0.f, 0.f}, {0.f, 0.f, 0.f, 0.f}};

    for (int k0 = 0; k0 < DD; k0 += TK) {
        #pragma unroll
        for (int i = 0; i < 4; ++i) {
            const int li = t + 256 * i;      // 0..1023
            const int kk = li >> 6;          // 0..15
            const int m  = li & 63;          // 0..63
            const int k  = k0 + kk;
            const int r  = r0 + m;
            const int v   = r / 18;
            const int rem = r - v * 18;
            const int cat = rem / 6;
            const int lg  = rem - cat * 6;
            const float h = Aall[v * DD + k]
                          + Aall[(VV + cat) * DD + k]
                          + Aall[(VV + 3 + lg) * DD + k]
                          + b1[k];
            As[kk][m] = fmaxf(h, 0.f);
            Bs[kk][m] = W2[(size_t)k * DD + n0 + m];
        }
        __syncthreads();
        #pragma unroll
        for (int kk = 0; kk < TK; ++kk) {
            const float4 a = *(const float4*)&As[kk][ty * 4];
            const float4 b = *(const float4*)&Bs[kk][tx * 4];
            const float av[4] = {a.x, a.y, a.z, a.w};
            const float bv[4] = {b.x, b.y, b.z, b.w};
            #pragma unroll
            for (int i2 = 0; i2 < 4; ++i2)
                #pragma unroll
                for (int j = 0; j < 4; ++j)
                    acc[i2][j] += av[i2] * bv[j];
        }
        __syncthreads();
    }

    #pragma unroll
    for (int i = 0; i < 4; ++i) {
        const int r = r0 + ty * 4 + i;
        const int n = n0 + tx * 4;
        float4 o;
        o.x = acc[i][0] + b2[n + 0];
        o.y = acc[i][1] + b2[n + 1];
        o.z = acc[i][2] + b2[n + 2];
        o.w = acc[i][3] + b2[n + 3];
        *(float4*)&lut[(size_t)r * DD + n] = o;
    }
}

// ---------------------------------------------------------------------------
// Kernel 3: out[b,v,:] = lut[v*18 + idx[b,v], :]. Pure write-bandwidth.
// float4 per lane, 128 lanes per output row, grid-stride.
// ---------------------------------------------------------------------------
__global__ __launch_bounds__(256) void k_gather(
    const int* __restrict__ idx,
    const float* __restrict__ lut,
    float4* __restrict__ out)
{
    const size_t total  = (size_t)BB * VV * (DD / 4);  // 8388608 float4s
    const size_t stride = (size_t)gridDim.x * blockDim.x;
    for (size_t f = (size_t)blockIdx.x * blockDim.x + threadIdx.x; f < total; f += stride) {
        const size_t row  = f >> 7;          // (b*64+v)
        const int    lane = (int)(f & 127);
        const int    v    = (int)(row & 63);
        const int    id   = idx[row];
        const float4* src = (const float4*)(lut + (size_t)(v * 18 + id) * DD);
        out[f] = src[lane];
    }
}

// ---------------------------------------------------------------------------
extern "C" void kernel_launch(void* const* d_in, const int* in_sizes, int n_in,
                              void* d_out, int out_size, void* d_ws, size_t ws_size,
                              hipStream_t stream)
{
    const float* cm    = (const float*)d_in[0];
    const float* var_t = (const float*)d_in[1];
    const float* str_t = (const float*)d_in[2];
    const float* lag_t = (const float*)d_in[3];
    const float* W1    = (const float*)d_in[4];
    const float* b1    = (const float*)d_in[5];
    const float* W2    = (const float*)d_in[6];
    const float* b2    = (const float*)d_in[7];
    float4* out = (float4*)d_out;

    char*  ws   = (char*)d_ws;
    int*   idx  = (int*)ws;                   // 1024*64*4   = 262144 B
    float* Aall = (float*)(ws + 262144);      // 73*512*4    = 149504 B
    float* lut  = (float*)(ws + 524288);      // 1152*512*4  = 2359296 B  (total < 3 MB)

    k_reduce_a<<<BB + VV + 3 + LL, 384, 0, stream>>>(cm, var_t, str_t, lag_t, W1, idx, Aall);

    dim3 g2(NROWS / 64, DD / 64);
    k_lut<<<g2, 256, 0, stream>>>(Aall, b1, W2, b2, lut);

    k_gather<<<2048, 256, 0, stream>>>(idx, lut, out);
}

// Round 7
// 305.024 us; speedup vs baseline: 1.0359x; 1.0359x over previous
//
#include <hip/hip_runtime.h>
#include <math.h>

// Problem constants (B, V, L1, D from the reference)
#define BB 1024
#define VV 64
#define LL 6
#define DD 512
#define CM_STRIDE_B (VV * VV * LL)  // 24576 floats per batch slab
#define CM_STRIDE_C (VV * LL)       // 384 floats per cause row
#define NROWS (VV * 3 * LL)         // 1152 distinct (v,cat,lag) rows

// clang vector type: __builtin_nontemporal_* requires scalar/clang-vector,
// not HIP_vector_type (round-4 compile error).
typedef float f32x4 __attribute__((ext_vector_type(4)));

// ---------------------------------------------------------------------------
// Kernel 1 (fused): blocks [0,1024) reduce the causal matrix; blocks
// [1024,1097) compute the 73 "A" rows (table_row @ W1-slice).
//
// Reduce path: float4 non-temporal loads. 384 threads x 16 B = 1536 floats
// per step = 4 cause-rows; 16 steps cover all 64 causes. 1536 % 384 == 0, so
// each thread's 4 elements sit at FIXED within-row positions r0..r0+3 and a
// fixed cause-residue group g = t/96. Per-thread fp64 accumulation, then a
// 2-stage LDS combine. fp64 keeps the discrete cat/lag decisions exact
// (a flipped decision is a full-row 2e-2 error vs 4.7e-4 threshold).
// ---------------------------------------------------------------------------
__global__ __launch_bounds__(384) void k_reduce_a(
    const float* __restrict__ cm,
    const float* __restrict__ var_t,
    const float* __restrict__ str_t,
    const float* __restrict__ lag_t,
    const float* __restrict__ W1,
    int* __restrict__ idx,
    float* __restrict__ Aall)
{
    __shared__ double ssl[4][384];   // 12 KB
    __shared__ double asl[4][384];   // 12 KB
    __shared__ float  sin_[DD];      //  2 KB (A-block path only)

    const int blk = blockIdx.x;
    const int t   = threadIdx.x;

    if (blk < BB) {
        const f32x4* p4 = (const f32x4*)(cm + (size_t)blk * CM_STRIDE_B);
        double ss0 = 0.0, ss1 = 0.0, ss2 = 0.0, ss3 = 0.0;
        double as0 = 0.0, as1 = 0.0, as2 = 0.0, as3 = 0.0;
        #pragma unroll
        for (int step = 0; step < 16; ++step) {
            // streaming data, read exactly once: non-temporal
            const f32x4 x = __builtin_nontemporal_load(&p4[t + 384 * step]);
            ss0 += (double)x.x; as0 += fabs((double)x.x);
            ss1 += (double)x.y; as1 += fabs((double)x.y);
            ss2 += (double)x.z; as2 += fabs((double)x.z);
            ss3 += (double)x.w; as3 += fabs((double)x.w);
        }
        const int g  = t / 96;          // cause-residue group (c = g + 4*step)
        const int r0 = (4 * t) % 384;   // within-row slot of element 0
        ssl[g][r0 + 0] = ss0; asl[g][r0 + 0] = as0;
        ssl[g][r0 + 1] = ss1; asl[g][r0 + 1] = as1;
        ssl[g][r0 + 2] = ss2; asl[g][r0 + 2] = as2;
        ssl[g][r0 + 3] = ss3; asl[g][r0 + 3] = as3;
        __syncthreads();
        // per-slot totals over the 4 groups; slot t = (v = t/6, l = t%6)
        const double sst = ssl[0][t] + ssl[1][t] + ssl[2][t] + ssl[3][t];
        const double ast = asl[0][t] + asl[1][t] + asl[2][t] + asl[3][t];
        __syncthreads();
        ssl[0][t] = sst;
        asl[0][t] = ast;
        __syncthreads();
        if (t < VV) {
            const int base = t * LL;
            double m = 0.0;
            #pragma unroll
            for (int l = 0; l < LL; ++l) m += ssl[0][base + l];
            m *= (1.0 / (double)(VV * LL));
            const int cat = (m > 0.1) ? 1 : ((m < -0.1) ? 2 : 0);
            double best = asl[0][base];
            int bl = 0;
            #pragma unroll
            for (int l = 1; l < LL; ++l) {          // strict > == first-occurrence argmax
                const double s = asl[0][base + l];
                if (s > best) { best = s; bl = l; }
            }
            idx[blk * VV + t] = cat * LL + bl;      // packed in [0,18)
        }
    } else {
        const int r = blk - BB;                     // 0..72
        const float* in;
        const float* W;
        if (r < VV)          { in = var_t + r * DD;            W = W1; }
        else if (r < VV + 3) { in = str_t + (r - VV) * DD;     W = W1 + (size_t)DD * DD; }
        else                 { in = lag_t + (r - VV - 3) * DD; W = W1 + (size_t)2 * DD * DD; }
        for (int k = t; k < DD; k += 384) sin_[k] = in[k];
        __syncthreads();
        for (int d = t; d < DD; d += 384) {
            float acc = 0.f;
            for (int k = 0; k < DD; ++k) acc += sin_[k] * W[(size_t)k * DD + d];
            Aall[r * DD + d] = acc;
        }
    }
}

// ---------------------------------------------------------------------------
// Kernel 2: lut[1152][512] = relu(h) @ W2 + b2, with
//   h[r][k] = A1[v(r)][k] + A2[cat(r)][k] + A3[lag(r)][k] + b1[k]
// computed on the fly (Aall is 146 KB, L2-hot). 64x64 fp32 tile, 256 threads,
// 4x4 micro-tile, K-tiles of 16. Row-index math hoisted out of the K loop.
// ---------------------------------------------------------------------------
#define TK 16
__global__ __launch_bounds__(256) void k_lut(
    const float* __restrict__ Aall,
    const float* __restrict__ b1,
    const float* __restrict__ W2,
    const float* __restrict__ b2,
    float* __restrict__ lut)
{
    __shared__ float As[TK][64];
    __shared__ float Bs[TK][64];

    const int r0 = blockIdx.x * 64;
    const int n0 = blockIdx.y * 64;
    const int t  = threadIdx.x;
    const int tx = t & 15;
    const int ty = t >> 4;

    // per-staging-element constants (independent of k0)
    int kkc[4], mc[4], offv[4], offc[4], offl[4];
    #pragma unroll
    for (int i = 0; i < 4; ++i) {
        const int li = t + 256 * i;      // 0..1023
        kkc[i] = li >> 6;                // 0..15
        mc[i]  = li & 63;                // 0..63
        const int r   = r0 + mc[i];
        const int v   = r / 18;
        const int rem = r - v * 18;
        const int cat = rem / 6;
        const int lg  = rem - cat * 6;
        offv[i] = v * DD;
        offc[i] = (VV + cat) * DD;
        offl[i] = (VV + 3 + lg) * DD;
    }

    float acc[4][4] = {{0.f, 0.f, 0.f, 0.f}, {0.f, 0.f, 0.f, 0.f},
                       {0.f, 0.f, 0.f, 0.f}, {0.f, 0.f, 0.f, 0.f}};

    for (int k0 = 0; k0 < DD; k0 += TK) {
        #pragma unroll
        for (int i = 0; i < 4; ++i) {
            const int k = k0 + kkc[i];
            const float h = Aall[offv[i] + k]
                          + Aall[offc[i] + k]
                          + Aall[offl[i] + k]
                          + b1[k];
            As[kkc[i]][mc[i]] = fmaxf(h, 0.f);
            Bs[kkc[i]][mc[i]] = W2[(size_t)k * DD + n0 + mc[i]];
        }
        __syncthreads();
        #pragma unroll
        for (int kk = 0; kk < TK; ++kk) {
            const float4 a = *(const float4*)&As[kk][ty * 4];
            const float4 b = *(const float4*)&Bs[kk][tx * 4];
            const float av[4] = {a.x, a.y, a.z, a.w};
            const float bv[4] = {b.x, b.y, b.z, b.w};
            #pragma unroll
            for (int i2 = 0; i2 < 4; ++i2)
                #pragma unroll
                for (int j = 0; j < 4; ++j)
                    acc[i2][j] += av[i2] * bv[j];
        }
        __syncthreads();
    }

    #pragma unroll
    for (int i = 0; i < 4; ++i) {
        const int r = r0 + ty * 4 + i;
        const int n = n0 + tx * 4;
        float4 o;
        o.x = acc[i][0] + b2[n + 0];
        o.y = acc[i][1] + b2[n + 1];
        o.z = acc[i][2] + b2[n + 2];
        o.w = acc[i][3] + b2[n + 3];
        *(float4*)&lut[(size_t)r * DD + n] = o;
    }
}

// ---------------------------------------------------------------------------
// Kernel 3: out[b,v,:] = lut[v*18 + idx[b,v], :]. Pure write-bandwidth.
// Non-temporal 16B stores (streamed once, keep L2 for lut reads).
// ---------------------------------------------------------------------------
__global__ __launch_bounds__(256) void k_gather(
    const int* __restrict__ idx,
    const float* __restrict__ lut,
    f32x4* __restrict__ out)
{
    const size_t total  = (size_t)BB * VV * (DD / 4);  // 8388608 float4s
    const size_t stride = (size_t)gridDim.x * blockDim.x;
    for (size_t f = (size_t)blockIdx.x * blockDim.x + threadIdx.x; f < total; f += stride) {
        const size_t row  = f >> 7;          // (b*64+v)
        const int    lane = (int)(f & 127);
        const int    v    = (int)(row & 63);
        const int    id   = idx[row];
        const f32x4* src = (const f32x4*)(lut + (size_t)(v * 18 + id) * DD);
        __builtin_nontemporal_store(src[lane], &out[f]);
    }
}

// ---------------------------------------------------------------------------
extern "C" void kernel_launch(void* const* d_in, const int* in_sizes, int n_in,
                              void* d_out, int out_size, void* d_ws, size_t ws_size,
                              hipStream_t stream)
{
    const float* cm    = (const float*)d_in[0];
    const float* var_t = (const float*)d_in[1];
    const float* str_t = (const float*)d_in[2];
    const float* lag_t = (const float*)d_in[3];
    const float* W1    = (const float*)d_in[4];
    const float* b1    = (const float*)d_in[5];
    const float* W2    = (const float*)d_in[6];
    const float* b2    = (const float*)d_in[7];
    f32x4* out = (f32x4*)d_out;

    char*  ws   = (char*)d_ws;
    int*   idx  = (int*)ws;                   // 1024*64*4   = 262144 B
    float* Aall = (float*)(ws + 262144);      // 73*512*4    = 149504 B
    float* lut  = (float*)(ws + 524288);      // 1152*512*4  = 2359296 B  (total < 3 MB)

    k_reduce_a<<<BB + VV + 3 + LL, 384, 0, stream>>>(cm, var_t, str_t, lag_t, W1, idx, Aall);

    dim3 g2(NROWS / 64, DD / 64);
    k_lut<<<g2, 256, 0, stream>>>(Aall, b1, W2, b2, lut);

    k_gather<<<2048, 256, 0, stream>>>(idx, lut, out);
}